// Round 7
// baseline (8143.955 us; speedup 1.0000x reference)
//
#include <hip/hip_runtime.h>
#include <hip/hip_cooperative_groups.h>
#include <math.h>

#define BB 32
#define LL 40
#define DD 128
#define NSB 64                        // 2 seq * 32 batch
#define NU  (NSB * LL)                // 2560
#define PLANE (DD * DD)               // 16384
#define SLAB ((size_t)NSB * PLANE)    // u16 elements per t-slab (2 MB)

typedef unsigned short u16;
typedef unsigned int u32;

__device__ __forceinline__ u16 f2bf(float f) {
    union { float f; unsigned u; } v; v.f = f;
    unsigned u = v.u;
    u += 0x7fff + ((u >> 16) & 1);    // RNE
    return (u16)(u >> 16);
}
__device__ __forceinline__ float bf2f(u16 b) {
    union { unsigned u; float f; } v; v.u = ((unsigned)b) << 16;
    return v.f;
}
__device__ __forceinline__ float sigm(float x)  { return 1.f / (1.f + __expf(-x)); }
// tanh(x) = 2*sigmoid(2x)-1 ; safe at extremes
__device__ __forceinline__ float tanhs(float x) { return 2.f / (1.f + __expf(-2.f * x)) - 1.f; }

// ---------------- prep: xe rows + inverse squared norms ----------------
__global__ void prep_kernel(const int* __restrict__ q, const int* __restrict__ a,
                            const float* __restrict__ embed,
                            float* __restrict__ xe_all, float* __restrict__ inv_all) {
    int u = blockIdx.x * 4 + (threadIdx.x >> 6);
    int lane = threadIdx.x & 63;
    if (u >= NU) return;
    int sb = u / LL, t = u % LL;
    int s = sb >> 5, b = sb & 31;
    const int* idx = s ? a : q;
    int e = idx[b * LL + t];
    const float* row = embed + (size_t)e * DD;
    float v0 = row[lane], v1 = row[lane + 64];
    xe_all[(size_t)u * DD + lane] = v0;
    xe_all[(size_t)u * DD + lane + 64] = v1;
    float d = v0 * v0 + v1 * v1;
    #pragma unroll
    for (int o = 32; o; o >>= 1) d += __shfl_down(d, o);
    if (lane == 0) inv_all[u] = 1.f / (d + 1e-4f);
}

// Shared per-step body: stage window into LDS. Returns via win[].
// Block mapping: slot (0: layer1 @ u, 1: layer2 @ u), sb, k -> rows 16k..16k+15.
__device__ __forceinline__
void stage_window(float (*win)[130], int tid, int slot, int sb, int r0, int u,
                  const float* __restrict__ xe_all, const float* __restrict__ inv_all,
                  const u16* __restrict__ h1, const u16* __restrict__ hown) {
    const float* xe_g = xe_all + (size_t)(sb * LL + u) * DD;
    const float invv = (slot == 0) ? inv_all[sb * LL + u] : 0.f;
    const u16* ownprev = hown + (size_t)u * SLAB + (size_t)sb * PLANE;       // time u-1
    const u16* xtsrc   = h1 + (size_t)(u + 1) * SLAB + (size_t)sb * PLANE;   // h1[u]
    for (int e = tid; e < 34 * 64; e += 256) {
        int lr = e >> 6, cp = e & 63;
        int cr = 2 * r0 - 1 + lr;
        int c0 = 2 * cp;
        float v0 = 0.f, v1 = 0.f;
        if (cr >= 0 && cr < 256) {
            if (cr < 128) {
                if (slot == 0) {            // density row: inv * xe[cr] * xe[c]
                    float xr = xe_g[cr] * invv;
                    v0 = xr * xe_g[c0]; v1 = xr * xe_g[c0 + 1];
                } else {                     // xt = h1[u]
                    u32 p = *(const u32*)(xtsrc + (size_t)cr * DD + c0);
                    v0 = bf2f((u16)p); v1 = bf2f((u16)(p >> 16));
                }
            } else {                         // own h at u-1
                u32 p = *(const u32*)(ownprev + (size_t)(cr - 128) * DD + c0);
                v0 = bf2f((u16)p); v1 = bf2f((u16)(p >> 16));
            }
        }
        win[lr][c0 + 1] = v0;
        win[lr][c0 + 2] = v1;
    }
}

// ---------------- cooperative: whole 2-layer conv-LSTM in one kernel ----------------
// Grid 1024 x 256 (4 blocks/CU). Block b: slot=b>>9, sb=(b>>3)&63, k=b&7.
// Thread (tx=tid&127, th=tid>>7): rows r0+2j+th, col tx. c/pool in registers.
// h slab s holds time s-1 (slab 0 zeroed). Agent-scope fences around grid.sync
// make cross-XCD h traffic coherent (per-XCD L2s are not coherent by default).
__global__ __launch_bounds__(256, 4)
void coop_kernel(const float* __restrict__ xe_all, const float* __restrict__ inv_all,
                 const float* __restrict__ conv_w, const float* __restrict__ conv_b,
                 u16* __restrict__ h1, u16* __restrict__ h2, float* __restrict__ pool) {
    cooperative_groups::grid_group grid = cooperative_groups::this_grid();
    const int blk = blockIdx.x;
    const int slot = blk >> 9;
    const int sb = (blk >> 3) & 63;
    const int k = blk & 7;
    const int r0 = k * 16;
    const int tid = threadIdx.x;
    const int tx = tid & 127;
    const int th = tid >> 7;

    __shared__ float win[34][130];     // concat rows 2*r0-1 .. 2*r0+32, data at [c+1]

    float w[48], b4[4];
    #pragma unroll
    for (int i = 0; i < 48; ++i) w[i] = conv_w[slot * 48 + i];
    #pragma unroll
    for (int i = 0; i < 4; ++i) b4[i] = conv_b[slot * 4 + i];
    for (int e = tid; e < 34; e += 256) { win[e][0] = 0.f; win[e][129] = 0.f; }

    u16* hown = slot ? h2 : h1;

    float c8[8], pr8[8];
    #pragma unroll
    for (int j = 0; j < 8; ++j) { c8[j] = 0.f; pr8[j] = -1e30f; }

    for (int step = 0; step <= LL; ++step) {
        const int u = slot ? (step - 1) : step;
        const bool act = (u >= 0 && u < LL);
        if (act)
            stage_window(win, tid, slot, sb, r0, u, xe_all, inv_all, h1, hown);
        __syncthreads();
        if (act) {
            u16* hdst = hown + (size_t)(u + 1) * SLAB + (size_t)sb * PLANE;
            #pragma unroll
            for (int j = 0; j < 8; ++j) {
                const int lw = 4 * j + 2 * th;
                float a0 = b4[0], a1 = b4[1], a2 = b4[2], a3 = b4[3];
                #pragma unroll
                for (int kh = 0; kh < 4; ++kh) {
                    #pragma unroll
                    for (int kw = 0; kw < 3; ++kw) {
                        float v = win[lw + kh][tx + kw];
                        a0 += v * w[kh * 3 + kw];
                        a1 += v * w[12 + kh * 3 + kw];
                        a2 += v * w[24 + kh * 3 + kw];
                        a3 += v * w[36 + kh * 3 + kw];
                    }
                }
                float fg = sigm(a0), ig = sigm(a1), og = sigm(a2), cs = tanhs(a3);
                c8[j] = fg * c8[j] + ig * cs;
                float hn = og * tanhs(c8[j]);
                hdst[(size_t)(r0 + 2 * j + th) * DD + tx] = f2bf(hn);
                pr8[j] = fmaxf(pr8[j], hn);
            }
        }
        // release: force this XCD's L2 to write back h before others read it
        __builtin_amdgcn_fence(__ATOMIC_RELEASE, "agent");
        grid.sync();
        // acquire: invalidate stale h lines cached in this XCD's L2
        __builtin_amdgcn_fence(__ATOMIC_ACQUIRE, "agent");
    }
    if (slot == 1) {
        #pragma unroll
        for (int j = 0; j < 8; ++j)
            pool[(size_t)sb * PLANE + (size_t)(r0 + 2 * j + th) * DD + tx] = pr8[j];
    }
}

// ---------------- fallback: one pipelined step per launch (no coop needed) ----------------
// Same mapping as coop_kernel; c lives in f32 workspace, pool via fmax in global.
__global__ __launch_bounds__(256)
void step_kernel(const float* __restrict__ xe_all, const float* __restrict__ inv_all,
                 const float* __restrict__ conv_w, const float* __restrict__ conv_b,
                 u16* __restrict__ h1, u16* __restrict__ h2,
                 float* __restrict__ cbuf, float* __restrict__ pool, int step) {
    const int blk = blockIdx.x;
    const int slot = blk >> 9;
    const int sb = (blk >> 3) & 63;
    const int k = blk & 7;
    const int r0 = k * 16;
    const int tid = threadIdx.x;
    const int tx = tid & 127;
    const int th = tid >> 7;
    const int u = slot ? (step - 1) : step;
    if (u < 0 || u >= LL) return;

    __shared__ float win[34][130];
    for (int e = tid; e < 34; e += 256) { win[e][0] = 0.f; win[e][129] = 0.f; }

    u16* hown = slot ? h2 : h1;
    stage_window(win, tid, slot, sb, r0, u, xe_all, inv_all, h1, hown);
    __syncthreads();

    float w[48], b4[4];
    #pragma unroll
    for (int i = 0; i < 48; ++i) w[i] = conv_w[slot * 48 + i];
    #pragma unroll
    for (int i = 0; i < 4; ++i) b4[i] = conv_b[slot * 4 + i];

    u16* hdst = hown + (size_t)(u + 1) * SLAB + (size_t)sb * PLANE;
    float* cp = cbuf + (size_t)slot * NSB * PLANE + (size_t)sb * PLANE;
    #pragma unroll
    for (int j = 0; j < 8; ++j) {
        const int lw = 4 * j + 2 * th;
        float a0 = b4[0], a1 = b4[1], a2 = b4[2], a3 = b4[3];
        #pragma unroll
        for (int kh = 0; kh < 4; ++kh) {
            #pragma unroll
            for (int kw = 0; kw < 3; ++kw) {
                float v = win[lw + kh][tx + kw];
                a0 += v * w[kh * 3 + kw];
                a1 += v * w[12 + kh * 3 + kw];
                a2 += v * w[24 + kh * 3 + kw];
                a3 += v * w[36 + kh * 3 + kw];
            }
        }
        float fg = sigm(a0), ig = sigm(a1), og = sigm(a2), cs = tanhs(a3);
        const size_t px = (size_t)(r0 + 2 * j + th) * DD + tx;
        float c_old = (u > 0) ? cp[px] : 0.f;
        float cn = fg * c_old + ig * cs;
        float hn = og * tanhs(cn);
        cp[px] = cn;
        hdst[px] = f2bf(hn);
        if (slot == 1) {
            float* pp = pool + (size_t)sb * PLANE + px;
            *pp = (u == 0) ? hn : fmaxf(*pp, hn);
        }
    }
}

// ---------------- final: linear + log_softmax ----------------
__global__ void final_kernel(const float* __restrict__ pool,
                             const float* __restrict__ lin_w,
                             const float* __restrict__ lin_b,
                             float* __restrict__ out) {
    const int b = blockIdx.x;
    const int tid = threadIdx.x;  // 256
    const int DD2 = DD * DD;
    const float* pq = pool + (size_t)b * DD2;
    const float* pa = pool + (size_t)(BB + b) * DD2;
    float s0 = 0.f, s1 = 0.f;
    for (int j = tid; j < DD2; j += 256) {
        float vq = pq[j], va = pa[j];
        s0 += vq * lin_w[j]           + va * lin_w[DD2 + j];
        s1 += vq * lin_w[2 * DD2 + j] + va * lin_w[3 * DD2 + j];
    }
    #pragma unroll
    for (int o = 32; o; o >>= 1) {
        s0 += __shfl_down(s0, o);
        s1 += __shfl_down(s1, o);
    }
    __shared__ float sh0[4], sh1[4];
    int wid = tid >> 6, lane = tid & 63;
    if (lane == 0) { sh0[wid] = s0; sh1[wid] = s1; }
    __syncthreads();
    if (tid == 0) {
        float a0 = sh0[0] + sh0[1] + sh0[2] + sh0[3] + lin_b[0];
        float a1 = sh1[0] + sh1[1] + sh1[2] + sh1[3] + lin_b[1];
        float m = fmaxf(a0, a1);
        float lse = m + logf(expf(a0 - m) + expf(a1 - m));
        out[b * 2 + 0] = a0 - lse;
        out[b * 2 + 1] = a1 - lse;
    }
}

extern "C" void kernel_launch(void* const* d_in, const int* in_sizes, int n_in,
                              void* d_out, int out_size, void* d_ws, size_t ws_size,
                              hipStream_t stream) {
    const int*   q      = (const int*)d_in[0];
    const int*   a      = (const int*)d_in[1];
    const float* embed  = (const float*)d_in[2];
    const float* conv_w = (const float*)d_in[3];
    const float* conv_b = (const float*)d_in[4];
    const float* lin_w  = (const float*)d_in[5];
    const float* lin_b  = (const float*)d_in[6];
    float* out = (float*)d_out;

    // ws: xe 1.31MB | inv 10KB | pool 4.19MB | h1 86MB | h2 86MB | cbuf 8.4MB => ~186MB
    float* ws      = (float*)d_ws;
    float* xe_all  = ws;
    float* inv_all = xe_all + (size_t)NU * DD;
    float* pool    = inv_all + NU;
    u16*   h1      = (u16*)(pool + (size_t)NSB * PLANE);
    u16*   h2      = h1 + (size_t)(LL + 1) * SLAB;
    float* cbuf    = (float*)(h2 + (size_t)(LL + 1) * SLAB);

    // zero the t = -1 slabs
    hipMemsetAsync(h1, 0, SLAB * sizeof(u16), stream);
    hipMemsetAsync(h2, 0, SLAB * sizeof(u16), stream);

    prep_kernel<<<(NU + 3) / 4, 256, 0, stream>>>(q, a, embed, xe_all, inv_all);

    void* args[] = {(void*)&xe_all, (void*)&inv_all, (void*)&conv_w, (void*)&conv_b,
                    (void*)&h1, (void*)&h2, (void*)&pool};
    hipError_t cerr = hipLaunchCooperativeKernel((void*)coop_kernel, dim3(1024), dim3(256),
                                                 args, 0, stream);
    if (cerr != hipSuccess) {
        // fallback: 41 pipelined step launches (no grid-wide sync required)
        for (int step = 0; step <= LL; ++step)
            step_kernel<<<dim3(1024), dim3(256), 0, stream>>>(
                xe_all, inv_all, conv_w, conv_b, h1, h2, cbuf, pool, step);
    }

    final_kernel<<<BB, 256, 0, stream>>>(pool, lin_w, lin_b, out);
}

// Round 8
// 987.371 us; speedup vs baseline: 8.2481x; 8.2481x over previous
//
#include <hip/hip_runtime.h>
#include <math.h>

#define BB 32
#define LL 40
#define DD 128
#define NSB 64                        // 2 seq * 32 batch
#define NU  (NSB * LL)                // 2560
#define PLANE (DD * DD)               // 16384
#define SLAB ((size_t)NSB * PLANE)    // u16 elements per t-slab (2 MB)

typedef unsigned short u16;
typedef unsigned int u32;

__device__ __forceinline__ u16 f2bf(float f) {
    union { float f; unsigned u; } v; v.f = f;
    unsigned u = v.u;
    u += 0x7fff + ((u >> 16) & 1);    // RNE
    return (u16)(u >> 16);
}
__device__ __forceinline__ float bf2f(u16 b) {
    union { unsigned u; float f; } v; v.u = ((unsigned)b) << 16;
    return v.f;
}
__device__ __forceinline__ float sigm(float x)  { return 1.f / (1.f + __expf(-x)); }
// tanh(x) = 2*sigmoid(2x)-1 ; safe at extremes
__device__ __forceinline__ float tanhs(float x) { return 2.f / (1.f + __expf(-2.f * x)) - 1.f; }

#define CONV_ACC(v, kh, kw) \
    a0 = fmaf(v, w[(kh)*3+(kw)], a0); \
    a1 = fmaf(v, w[12+(kh)*3+(kw)], a1); \
    a2 = fmaf(v, w[24+(kh)*3+(kw)], a2); \
    a3 = fmaf(v, w[36+(kh)*3+(kw)], a3);

// ---------------- prep: xe rows + inverse squared norms ----------------
__global__ void prep_kernel(const int* __restrict__ q, const int* __restrict__ a,
                            const float* __restrict__ embed,
                            float* __restrict__ xe_all, float* __restrict__ inv_all) {
    int u = blockIdx.x * 4 + (threadIdx.x >> 6);
    int lane = threadIdx.x & 63;
    if (u >= NU) return;
    int sb = u / LL, t = u % LL;
    int s = sb >> 5, b = sb & 31;
    const int* idx = s ? a : q;
    int e = idx[b * LL + t];
    const float* row = embed + (size_t)e * DD;
    float v0 = row[lane], v1 = row[lane + 64];
    xe_all[(size_t)u * DD + lane] = v0;
    xe_all[(size_t)u * DD + lane + 64] = v1;
    float d = v0 * v0 + v1 * v1;
    #pragma unroll
    for (int o = 32; o; o >>= 1) d += __shfl_down(d, o);
    if (lane == 0) inv_all[u] = 1.f / (d + 1e-4f);
}

// ---------------- layer1 rows 0..62: fused gates+scan, density input ----------------
// Thread owns pixel (i, c); serial t; c in register. grid (32, NSB) x 256.
__global__ __launch_bounds__(256)
void lev0_l1_kernel(const float* __restrict__ xe_all, const float* __restrict__ inv_all,
                    const float* __restrict__ conv_w, const float* __restrict__ conv_b,
                    u16* __restrict__ h1) {
    const int sb = blockIdx.y;
    const int ty = threadIdx.x >> 7, tx = threadIdx.x & 127;
    const int i = 2 * blockIdx.x + ty;
    if (i >= 63) return;
    float w[48], b4[4];
    #pragma unroll
    for (int k = 0; k < 48; ++k) w[k] = conv_w[k];
    #pragma unroll
    for (int k = 0; k < 4; ++k) b4[k] = conv_b[k];
    const int rb = 2 * i - 1;
    const int rb0 = rb < 0 ? 0 : rb;          // clamp (i==0, kh==0)
    const bool r0ok = (rb >= 0);
    const bool cl = (tx > 0), cr = (tx < 127);
    const float* xe = xe_all + (size_t)(sb * LL) * DD;
    const float* invp = inv_all + sb * LL;
    u16* hp = h1 + SLAB + (size_t)sb * PLANE + (size_t)i * DD + tx;
    float creg = 0.f;
    for (int t = 0; t < LL; ++t) {
        const float inv = invp[t];
        float p0 = r0ok ? xe[rb0] : 0.f;
        float p1 = xe[rb + 1], p2 = xe[rb + 2], p3 = xe[rb + 3];
        p0 *= inv; p1 *= inv; p2 *= inv; p3 *= inv;
        const float xl = cl ? xe[tx - 1] : 0.f;
        const float xm = xe[tx];
        const float xr = cr ? xe[tx + 1] : 0.f;
        float a0 = b4[0], a1 = b4[1], a2 = b4[2], a3 = b4[3];
        float v;
        v = p0 * xl; CONV_ACC(v, 0, 0); v = p0 * xm; CONV_ACC(v, 0, 1); v = p0 * xr; CONV_ACC(v, 0, 2);
        v = p1 * xl; CONV_ACC(v, 1, 0); v = p1 * xm; CONV_ACC(v, 1, 1); v = p1 * xr; CONV_ACC(v, 1, 2);
        v = p2 * xl; CONV_ACC(v, 2, 0); v = p2 * xm; CONV_ACC(v, 2, 1); v = p2 * xr; CONV_ACC(v, 2, 2);
        v = p3 * xl; CONV_ACC(v, 3, 0); v = p3 * xm; CONV_ACC(v, 3, 1); v = p3 * xr; CONV_ACC(v, 3, 2);
        float fg = sigm(a0), ig = sigm(a1), og = sigm(a2), cs = tanhs(a3);
        creg = fg * creg + ig * cs;
        *hp = f2bf(og * tanhs(creg));
        hp += SLAB;
        xe += DD;
    }
}

// ---------------- generic fused level: direct global window reads ----------------
// mode is encoded by (rowOff, slabOff): xt-input (rowOff=-1, slabOff=1, src=h1)
// or own-h-at-(t-1) input (rowOff=-129, slabOff=0, src=own h).
// Thread owns pixel (i, c); serial t; c+poolmax in registers. No LDS, no barriers.
__global__ __launch_bounds__(256)
void lev_conv_kernel(const u16* __restrict__ src, u16* __restrict__ hdst,
                     float* __restrict__ pool,
                     const float* __restrict__ conv_w, const float* __restrict__ conv_b,
                     int layer, int r0, int nr, int rowOff, int slabOff) {
    const int sb = blockIdx.y;
    const int ty = threadIdx.x >> 7, tx = threadIdx.x & 127;
    const int i = r0 + 2 * blockIdx.x + ty;
    if (i >= r0 + nr) return;
    float w[48], b4[4];
    #pragma unroll
    for (int k = 0; k < 48; ++k) w[k] = conv_w[layer * 48 + k];
    #pragma unroll
    for (int k = 0; k < 4; ++k) b4[k] = conv_b[layer * 4 + k];
    const int rbase = 2 * i + rowOff;
    const u16* sp[4];
    bool rv[4];
    #pragma unroll
    for (int kh = 0; kh < 4; ++kh) {
        int r = rbase + kh;
        rv[kh] = (r >= 0);
        sp[kh] = src + (size_t)slabOff * SLAB + (size_t)sb * PLANE
               + (size_t)(r < 0 ? 0 : r) * DD + tx;
    }
    const bool cl = (tx > 0), cr = (tx < 127);
    u16* hp = hdst + SLAB + (size_t)sb * PLANE + (size_t)i * DD + tx;
    float creg = 0.f, pr = -1e30f;
    for (int t = 0; t < LL; ++t) {
        float a0 = b4[0], a1 = b4[1], a2 = b4[2], a3 = b4[3];
        #pragma unroll
        for (int kh = 0; kh < 4; ++kh) {
            const u16* p = sp[kh];
            float vl = (rv[kh] && cl) ? bf2f(p[-1]) : 0.f;
            float vm = rv[kh] ? bf2f(p[0]) : 0.f;
            float vr = (rv[kh] && cr) ? bf2f(p[1]) : 0.f;
            CONV_ACC(vl, kh, 0);
            CONV_ACC(vm, kh, 1);
            CONV_ACC(vr, kh, 2);
            sp[kh] += SLAB;
        }
        float fg = sigm(a0), ig = sigm(a1), og = sigm(a2), cs = tanhs(a3);
        creg = fg * creg + ig * cs;
        float hn = og * tanhs(creg);
        *hp = f2bf(hn);
        hp += SLAB;
        pr = fmaxf(pr, hn);
    }
    if (pool) pool[(size_t)sb * PLANE + (size_t)i * DD + tx] = pr;
}

// conv+LSTM update for one tail pixel from the LDS window
__device__ __forceinline__
float tail_px(const float (*wp)[130], const float* wls, const float* bls,
              int lr, int c, float& creg, float& pr) {
    float a0 = bls[0], a1 = bls[1], a2 = bls[2], a3 = bls[3];
    #pragma unroll
    for (int kh = 0; kh < 4; ++kh) {
        #pragma unroll
        for (int kw = 0; kw < 3; ++kw) {
            float v = wp[lr + kh][c + kw];
            a0 = fmaf(v, wls[kh*3+kw], a0);
            a1 = fmaf(v, wls[12+kh*3+kw], a1);
            a2 = fmaf(v, wls[24+kh*3+kw], a2);
            a3 = fmaf(v, wls[36+kh*3+kw], a3);
        }
    }
    float fg = sigm(a0), ig = sigm(a1), og = sigm(a2), cs = tanhs(a3);
    creg = fg * creg + ig * cs;
    float hn = og * tanhs(creg);
    pr = fmaxf(pr, hn);
    return hn;
}

// ---------------- tail rows 111..127: serial t, own rows in LDS ping-pong ----------------
// grid (NSB) x 1024. Window concat rows 93..128 local; rows 93..110 staged from
// global each t (time t-1 = slab t), rows 111..127 from previous iteration's LDS.
__global__ __launch_bounds__(1024)
void tail_kernel(const u16* __restrict__ hsrc, u16* __restrict__ hdst,
                 float* __restrict__ pool,
                 const float* __restrict__ conv_w, const float* __restrict__ conv_b,
                 int layer) {
    const int sb = blockIdx.x;
    const int tid = threadIdx.x;
    __shared__ float win[2][36][130];   // local row lr = concat_row - 93 + ... rows 93..128; [c+1]
    __shared__ float wls[48], bls[4];
    if (tid < 48) wls[tid] = conv_w[layer * 48 + tid];
    if (tid < 4)  bls[tid] = conv_b[layer * 4 + tid];
    for (int e = tid; e < 2 * 36 * 130; e += 1024) ((float*)win)[e] = 0.f;

    const int c = tid & 127;
    const int rA = 111 + (tid >> 7);    // rows 111..118
    const int rB = rA + 8;              // rows 119..126
    const bool hasC = (tid < 128);      // row 127
    const int lrA = 2 * rA - 222;       // window start rows (local)
    const int lrB = 2 * rB - 222;
    const int lrC = 32;
    float cA = 0.f, cB = 0.f, cC = 0.f;
    float pA = -1e30f, pB = -1e30f, pC = -1e30f;

    for (int t = 0; t < LL; ++t) {
        const int p = t & 1;
        const u16* g = hsrc + (size_t)t * SLAB + (size_t)sb * PLANE + (size_t)93 * DD;
        __syncthreads();                      // prev compute done (reads of win[p] finished)
        for (int e = tid; e < 18 * 128; e += 1024)
            win[p][e >> 7][(e & 127) + 1] = bf2f(g[e]);
        __syncthreads();
        u16* hd = hdst ? hdst + (size_t)(t + 1) * SLAB + (size_t)sb * PLANE : nullptr;
        float hnA = tail_px(win[p], wls, bls, lrA, c, cA, pA);
        float hnB = tail_px(win[p], wls, bls, lrB, c, cB, pB);
        win[p ^ 1][18 + (rA - 111)][c + 1] = hnA;
        win[p ^ 1][18 + (rB - 111)][c + 1] = hnB;
        if (hd) {
            hd[(size_t)rA * DD + c] = f2bf(hnA);
            hd[(size_t)rB * DD + c] = f2bf(hnB);
        }
        if (hasC) {
            float hnC = tail_px(win[p], wls, bls, lrC, c, cC, pC);
            win[p ^ 1][34][c + 1] = hnC;
            if (hd) hd[(size_t)127 * DD + c] = f2bf(hnC);
        }
    }
    if (pool) {
        float* pb = pool + (size_t)sb * PLANE;
        pb[(size_t)rA * DD + c] = pA;
        pb[(size_t)rB * DD + c] = pB;
        if (hasC) pb[(size_t)127 * DD + c] = pC;
    }
}

// ---------------- final: linear + log_softmax ----------------
__global__ void final_kernel(const float* __restrict__ pool,
                             const float* __restrict__ lin_w,
                             const float* __restrict__ lin_b,
                             float* __restrict__ out) {
    const int b = blockIdx.x;
    const int tid = threadIdx.x;  // 256
    const int DD2 = DD * DD;
    const float* pq = pool + (size_t)b * DD2;
    const float* pa = pool + (size_t)(BB + b) * DD2;
    float s0 = 0.f, s1 = 0.f;
    for (int j = tid; j < DD2; j += 256) {
        float vq = pq[j], va = pa[j];
        s0 += vq * lin_w[j]           + va * lin_w[DD2 + j];
        s1 += vq * lin_w[2 * DD2 + j] + va * lin_w[3 * DD2 + j];
    }
    #pragma unroll
    for (int o = 32; o; o >>= 1) {
        s0 += __shfl_down(s0, o);
        s1 += __shfl_down(s1, o);
    }
    __shared__ float sh0[4], sh1[4];
    int wid = tid >> 6, lane = tid & 63;
    if (lane == 0) { sh0[wid] = s0; sh1[wid] = s1; }
    __syncthreads();
    if (tid == 0) {
        float a0 = sh0[0] + sh0[1] + sh0[2] + sh0[3] + lin_b[0];
        float a1 = sh1[0] + sh1[1] + sh1[2] + sh1[3] + lin_b[1];
        float m = fmaxf(a0, a1);
        float lse = m + logf(expf(a0 - m) + expf(a1 - m));
        out[b * 2 + 0] = a0 - lse;
        out[b * 2 + 1] = a1 - lse;
    }
}

extern "C" void kernel_launch(void* const* d_in, const int* in_sizes, int n_in,
                              void* d_out, int out_size, void* d_ws, size_t ws_size,
                              hipStream_t stream) {
    const int*   q      = (const int*)d_in[0];
    const int*   a      = (const int*)d_in[1];
    const float* embed  = (const float*)d_in[2];
    const float* conv_w = (const float*)d_in[3];
    const float* conv_b = (const float*)d_in[4];
    const float* lin_w  = (const float*)d_in[5];
    const float* lin_b  = (const float*)d_in[6];
    float* out = (float*)d_out;

    // ws: pool 4.2MB | xe 1.31MB | inv 10KB | h1 86MB (41 bf16 slabs) | h2 86MB  => ~178MB
    // (pool placed FIRST so xe_all[-1]/h[-1] halo reads stay inside the allocation)
    float* ws      = (float*)d_ws;
    float* pool    = ws;
    float* xe_all  = pool + (size_t)NSB * PLANE;
    float* inv_all = xe_all + (size_t)NU * DD;
    u16*   h1      = (u16*)(inv_all + NU);
    u16*   h2      = h1 + (size_t)(LL + 1) * SLAB;

    // zero the t = -1 slabs
    hipMemsetAsync(h1, 0, SLAB * sizeof(u16), stream);
    hipMemsetAsync(h2, 0, SLAB * sizeof(u16), stream);

    prep_kernel<<<(NU + 3) / 4, 256, 0, stream>>>(q, a, embed, xe_all, inv_all);

    // ---- layer 1 ----
    lev0_l1_kernel<<<dim3(32, NSB), 256, 0, stream>>>(xe_all, inv_all, conv_w, conv_b, h1);
    lev_conv_kernel<<<dim3(16, NSB), 256, 0, stream>>>(h1, h1, nullptr, conv_w, conv_b,
                                                       0, 63, 32, -129, 0);
    lev_conv_kernel<<<dim3(8, NSB), 256, 0, stream>>>(h1, h1, nullptr, conv_w, conv_b,
                                                      0, 95, 16, -129, 0);
    tail_kernel<<<NSB, 1024, 0, stream>>>(h1, h1, nullptr, conv_w, conv_b, 0);
    // ---- layer 2 ----
    lev_conv_kernel<<<dim3(32, NSB), 256, 0, stream>>>(h1, h2, pool, conv_w, conv_b,
                                                       1, 0, 63, -1, 1);
    lev_conv_kernel<<<dim3(16, NSB), 256, 0, stream>>>(h2, h2, pool, conv_w, conv_b,
                                                       1, 63, 32, -129, 0);
    lev_conv_kernel<<<dim3(8, NSB), 256, 0, stream>>>(h2, h2, pool, conv_w, conv_b,
                                                      1, 95, 16, -129, 0);
    tail_kernel<<<NSB, 1024, 0, stream>>>(h2, nullptr, pool, conv_w, conv_b, 1);

    final_kernel<<<BB, 256, 0, stream>>>(pool, lin_w, lin_b, out);
}

// Round 10
// 660.761 us; speedup vs baseline: 12.3251x; 1.4943x over previous
//
#include <hip/hip_runtime.h>
#include <math.h>

#define BB 32
#define LL 40
#define DD 128
#define NSB 64                        // 2 seq * 32 batch
#define NU  (NSB * LL)                // 2560
#define PLANE (DD * DD)               // 16384
#define SLAB ((size_t)NSB * PLANE)    // u16 elements per t-slab (2 MB)
#define GMAXR 32                      // gate scratch sized for 32 rows
#define GSLAB ((size_t)NSB * GMAXR * DD)

typedef unsigned short u16;
typedef unsigned int u32;

__device__ __forceinline__ u16 f2bf(float f) {
    union { float f; unsigned u; } v; v.f = f;
    unsigned u = v.u;
    u += 0x7fff + ((u >> 16) & 1);    // RNE
    return (u16)(u >> 16);
}
__device__ __forceinline__ float bf2f(u16 b) {
    union { unsigned u; float f; } v; v.u = ((unsigned)b) << 16;
    return v.f;
}
__device__ __forceinline__ float sigm(float x)  { return 1.f / (1.f + __expf(-x)); }
// tanh(x) = 2*sigmoid(2x)-1 ; safe at extremes
__device__ __forceinline__ float tanhs(float x) { return 2.f / (1.f + __expf(-2.f * x)) - 1.f; }

// ---------------- prep: xe rows + inverse squared norms ----------------
__global__ void prep_kernel(const int* __restrict__ q, const int* __restrict__ a,
                            const float* __restrict__ embed,
                            float* __restrict__ xe_all, float* __restrict__ inv_all) {
    int u = blockIdx.x * 4 + (threadIdx.x >> 6);
    int lane = threadIdx.x & 63;
    if (u >= NU) return;
    int sb = u / LL, t = u % LL;
    int s = sb >> 5, b = sb & 31;
    const int* idx = s ? a : q;
    int e = idx[b * LL + t];
    const float* row = embed + (size_t)e * DD;
    float v0 = row[lane], v1 = row[lane + 64];
    xe_all[(size_t)u * DD + lane] = v0;
    xe_all[(size_t)u * DD + lane + 64] = v1;
    float d = v0 * v0 + v1 * v1;
    #pragma unroll
    for (int o = 32; o; o >>= 1) d += __shfl_down(d, o);
    if (lane == 0) inv_all[u] = 1.f / (d + 1e-4f);
}

// ---------------- layer1 separable gates (xt-only rows, density rank-1) ----------------
// t-parallel: grid (LL, NSB), block 1024. Level rows [r0, r0+nr), all < 63.
__global__ __launch_bounds__(1024)
void sepgates_kernel(const float* __restrict__ xe_all, const float* __restrict__ inv_all,
                     const float* __restrict__ conv_w, const float* __restrict__ conv_b,
                     u16* __restrict__ gfg, u16* __restrict__ gic, u16* __restrict__ gog,
                     int r0, int nr) {
    const int t = blockIdx.x, sb = blockIdx.y;
    const int tid = threadIdx.x;
    __shared__ float xe_s[130];        // data at [c+1], pads 0
    __shared__ float U[GMAXR][12];
    __shared__ float wls[48], bls[4];
    if (tid < 48) wls[tid] = conv_w[tid];
    if (tid < 4)  bls[tid] = conv_b[tid];
    if (tid < 128) xe_s[tid + 1] = xe_all[((size_t)sb * LL + t) * DD + tid];
    if (tid == 128) { xe_s[0] = 0.f; xe_s[129] = 0.f; }
    __syncthreads();
    for (int e = tid; e < nr * 12; e += 1024) {
        int lr = e / 12, k = e - lr * 12;
        int g = k / 3, kw = k - g * 3;
        int base = 2 * (r0 + lr) - 1;
        float s = 0.f;
        #pragma unroll
        for (int kh = 0; kh < 4; ++kh) {
            int r = base + kh;
            float v = (r >= 0 && r < 128) ? xe_s[r + 1] : 0.f;
            s += wls[g * 12 + kh * 3 + kw] * v;
        }
        U[lr][k] = s;
    }
    __syncthreads();
    const float invv = inv_all[sb * LL + t];
    const size_t gb = ((size_t)t * NSB + sb) * ((size_t)nr * DD);
    const int npx = nr * DD;
    for (int px = tid; px < npx; px += 1024) {
        int lr = px >> 7, c = px & 127;
        float xl = xe_s[c], xm = xe_s[c + 1], xr = xe_s[c + 2];
        float a0 = bls[0] + invv * (U[lr][0] * xl + U[lr][1]  * xm + U[lr][2]  * xr);
        float a1 = bls[1] + invv * (U[lr][3] * xl + U[lr][4]  * xm + U[lr][5]  * xr);
        float a2 = bls[2] + invv * (U[lr][6] * xl + U[lr][7]  * xm + U[lr][8]  * xr);
        float a3 = bls[3] + invv * (U[lr][9] * xl + U[lr][10] * xm + U[lr][11] * xr);
        gfg[gb + px] = f2bf(sigm(a0));
        gic[gb + px] = f2bf(sigm(a1) * tanhs(a3));
        gog[gb + px] = f2bf(sigm(a2));
    }
}

// ---------------- generic gates: stage concat window rows into LDS, conv ----------------
// t-parallel: grid (LL, NSB), block min(1024, nr*128). Level rows [r0, r0+nr), nr<=32.
// Concat row cr: cr<128 -> xt at time t (layer1: density from xe; layer2: h1[t]);
//                cr>=128 -> own h row cr-128 at time t-1 (= slab t; slab 0 zeroed).
__global__ __launch_bounds__(1024)
void gates_kernel(const float* __restrict__ xe_all, const float* __restrict__ inv_all,
                  const float* __restrict__ conv_w, const float* __restrict__ conv_b,
                  const u16* __restrict__ xt_h1,   // layer2: h1 base; layer1: null (density)
                  const u16* __restrict__ h_own,
                  u16* __restrict__ gfg, u16* __restrict__ gic, u16* __restrict__ gog,
                  int layer, int r0, int nr) {
    const int t = blockIdx.x, sb = blockIdx.y;
    const int tid = threadIdx.x, NT = blockDim.x;
    const int rfirst = 2 * r0 - 1, rcount = 2 * nr + 2;
    __shared__ float win[66][132];     // data at [c+1]; pads [0],[129] zero
    __shared__ float xe_s[128];
    __shared__ float wls[48], bls[4];
    if (tid < 48) wls[tid] = conv_w[layer * 48 + tid];
    if (tid < 4)  bls[tid] = conv_b[layer * 4 + tid];
    float invv = 0.f;
    if (layer == 0) {
        for (int e = tid; e < 128; e += NT) xe_s[e] = xe_all[((size_t)sb * LL + t) * DD + e];
        invv = inv_all[sb * LL + t];
    }
    for (int e = tid; e < rcount; e += NT) { win[e][0] = 0.f; win[e][129] = 0.f; }
    __syncthreads();
    const u16* xt_base  = xt_h1 ? xt_h1 + (size_t)(t + 1) * SLAB + (size_t)sb * PLANE : nullptr;
    const u16* own_base = h_own + (size_t)t * SLAB + (size_t)sb * PLANE;
    for (int e = tid; e < rcount * 64; e += NT) {
        int lr = e >> 6, cp = e & 63, cr = rfirst + lr;
        float v0 = 0.f, v1 = 0.f;
        if (cr >= 0) {
            if (cr < 128) {
                if (layer == 0) {
                    float xr = xe_s[cr] * invv;
                    v0 = xr * xe_s[2 * cp]; v1 = xr * xe_s[2 * cp + 1];
                } else {
                    u32 p = *(const u32*)(xt_base + (size_t)cr * DD + 2 * cp);
                    v0 = bf2f((u16)p); v1 = bf2f((u16)(p >> 16));
                }
            } else {
                u32 p = *(const u32*)(own_base + (size_t)(cr - 128) * DD + 2 * cp);
                v0 = bf2f((u16)p); v1 = bf2f((u16)(p >> 16));
            }
        }
        win[lr][2 * cp + 1] = v0;
        win[lr][2 * cp + 2] = v1;
    }
    __syncthreads();
    const size_t gb = ((size_t)t * NSB + sb) * ((size_t)nr * DD);
    const int npx = nr * DD;
    for (int px = tid; px < npx; px += NT) {
        int lro = px >> 7, col = px & 127;
        float a0 = bls[0], a1 = bls[1], a2 = bls[2], a3 = bls[3];
        #pragma unroll
        for (int kh = 0; kh < 4; ++kh) {
            #pragma unroll
            for (int kw = 0; kw < 3; ++kw) {
                float v = win[2 * lro + kh][col + kw];
                a0 = fmaf(v, wls[kh * 3 + kw], a0);
                a1 = fmaf(v, wls[12 + kh * 3 + kw], a1);
                a2 = fmaf(v, wls[24 + kh * 3 + kw], a2);
                a3 = fmaf(v, wls[36 + kh * 3 + kw], a3);
            }
        }
        gfg[gb + px] = f2bf(sigm(a0));
        gic[gb + px] = f2bf(sigm(a1) * tanhs(a3));
        gog[gb + px] = f2bf(sigm(a2));
    }
}

// ---------------- scan: pointwise c-recurrence over t ----------------
// grid (nr, NSB), block 128 (one row per block). h slab s holds time s-1.
__global__ __launch_bounds__(128)
void scan_kernel(const u16* __restrict__ gfg, const u16* __restrict__ gic,
                 const u16* __restrict__ gog,
                 u16* __restrict__ h, float* __restrict__ pool, int r0, int nr) {
    const int lr = blockIdx.x, sb = blockIdx.y, c = threadIdx.x;
    const size_t step = (size_t)NSB * nr * DD;
    size_t gi = ((size_t)sb * nr + lr) * DD + c;
    u16* hp = h + SLAB + (size_t)sb * PLANE + (size_t)(r0 + lr) * DD + c;
    float cc = 0.f, pr = -1e30f;
    #pragma unroll 4
    for (int t = 0; t < LL; ++t) {
        float fg = bf2f(gfg[gi]), u = bf2f(gic[gi]), og = bf2f(gog[gi]);
        cc = fg * cc + u;
        float hn = og * tanhs(cc);
        *hp = f2bf(hn);
        pr = fmaxf(pr, hn);
        gi += step; hp += SLAB;
    }
    if (pool) pool[(size_t)sb * PLANE + (size_t)(r0 + lr) * DD + c] = pr;
}

// ---------------- tail: rows 126..127 (self-recurrent), serial t ----------------
// grid (NSB), block 256. Window = h rows 123..128: 123..125 staged from global
// (t-1 = slab t), 126..127 own LDS ping-pong, 128 zero pad.
__global__ __launch_bounds__(256)
void tail2_kernel(const u16* __restrict__ hsrc, u16* __restrict__ hdst,
                  float* __restrict__ pool,
                  const float* __restrict__ conv_w, const float* __restrict__ conv_b,
                  int layer) {
    const int sb = blockIdx.x;
    const int tid = threadIdx.x;
    const int r = 126 + (tid >> 7), c = tid & 127;
    __shared__ float win2[2][6][130];   // rows h123..h128, data at [c+1]
    __shared__ float wls[48], bls[4];
    if (tid < 48) wls[tid] = conv_w[layer * 48 + tid];
    if (tid < 4)  bls[tid] = conv_b[layer * 4 + tid];
    for (int e = tid; e < 2 * 6 * 130; e += 256) ((float*)win2)[e] = 0.f;
    const int lr0 = (r == 126) ? 0 : 2;
    float creg = 0.f, pr = -1e30f;
    for (int t = 0; t < LL; ++t) {
        const int p = t & 1;
        const u16* g = hsrc + (size_t)t * SLAB + (size_t)sb * PLANE + (size_t)123 * DD;
        __syncthreads();                 // prev iteration's reads done
        for (int e = tid; e < 384; e += 256)
            win2[p][e >> 7][(e & 127) + 1] = bf2f(g[e]);
        __syncthreads();
        float a0 = bls[0], a1 = bls[1], a2 = bls[2], a3 = bls[3];
        #pragma unroll
        for (int kh = 0; kh < 4; ++kh) {
            #pragma unroll
            for (int kw = 0; kw < 3; ++kw) {
                float v = win2[p][lr0 + kh][c + kw];
                a0 = fmaf(v, wls[kh * 3 + kw], a0);
                a1 = fmaf(v, wls[12 + kh * 3 + kw], a1);
                a2 = fmaf(v, wls[24 + kh * 3 + kw], a2);
                a3 = fmaf(v, wls[36 + kh * 3 + kw], a3);
            }
        }
        float fg = sigm(a0), ig = sigm(a1), og = sigm(a2), cs = tanhs(a3);
        creg = fg * creg + ig * cs;
        float hn = og * tanhs(creg);
        win2[p ^ 1][3 + (r - 126)][c + 1] = hn;
        if (hdst) hdst[(size_t)(t + 1) * SLAB + (size_t)sb * PLANE + (size_t)r * DD + c] = f2bf(hn);
        pr = fmaxf(pr, hn);
    }
    if (pool) pool[(size_t)sb * PLANE + (size_t)r * DD + c] = pr;
}

// ---------------- final: linear + log_softmax ----------------
__global__ void final_kernel(const float* __restrict__ pool,
                             const float* __restrict__ lin_w,
                             const float* __restrict__ lin_b,
                             float* __restrict__ out) {
    const int b = blockIdx.x;
    const int tid = threadIdx.x;  // 256
    const int DD2 = DD * DD;
    const float* pq = pool + (size_t)b * DD2;
    const float* pa = pool + (size_t)(BB + b) * DD2;
    float s0 = 0.f, s1 = 0.f;
    for (int j = tid; j < DD2; j += 256) {
        float vq = pq[j], va = pa[j];
        s0 += vq * lin_w[j]           + va * lin_w[DD2 + j];
        s1 += vq * lin_w[2 * DD2 + j] + va * lin_w[3 * DD2 + j];
    }
    #pragma unroll
    for (int o = 32; o; o >>= 1) {
        s0 += __shfl_down(s0, o);
        s1 += __shfl_down(s1, o);
    }
    __shared__ float sh0[4], sh1[4];
    int wid = tid >> 6, lane = tid & 63;
    if (lane == 0) { sh0[wid] = s0; sh1[wid] = s1; }
    __syncthreads();
    if (tid == 0) {
        float a0 = sh0[0] + sh0[1] + sh0[2] + sh0[3] + lin_b[0];
        float a1 = sh1[0] + sh1[1] + sh1[2] + sh1[3] + lin_b[1];
        float m = fmaxf(a0, a1);
        float lse = m + logf(expf(a0 - m) + expf(a1 - m));
        out[b * 2 + 0] = a0 - lse;
        out[b * 2 + 1] = a1 - lse;
    }
}

extern "C" void kernel_launch(void* const* d_in, const int* in_sizes, int n_in,
                              void* d_out, int out_size, void* d_ws, size_t ws_size,
                              hipStream_t stream) {
    const int*   q      = (const int*)d_in[0];
    const int*   a      = (const int*)d_in[1];
    const float* embed  = (const float*)d_in[2];
    const float* conv_w = (const float*)d_in[3];
    const float* conv_b = (const float*)d_in[4];
    const float* lin_w  = (const float*)d_in[5];
    const float* lin_b  = (const float*)d_in[6];
    float* out = (float*)d_out;

    // ws: pool 4.2 | xe 1.31 | inv | h1 86 | h2 86 | gates 3x21  => ~240.4 MB
    float* ws      = (float*)d_ws;
    float* pool    = ws;
    float* xe_all  = pool + (size_t)NSB * PLANE;
    float* inv_all = xe_all + (size_t)NU * DD;
    u16*   h1      = (u16*)(inv_all + NU);
    u16*   h2      = h1 + (size_t)(LL + 1) * SLAB;
    u16*   gfg     = h2 + (size_t)(LL + 1) * SLAB;
    u16*   gic     = gfg + GSLAB * LL;
    u16*   gog     = gic + GSLAB * LL;

    // zero the t = -1 slabs
    hipMemsetAsync(h1, 0, SLAB * sizeof(u16), stream);
    hipMemsetAsync(h2, 0, SLAB * sizeof(u16), stream);

    prep_kernel<<<(NU + 3) / 4, 256, 0, stream>>>(q, a, embed, xe_all, inv_all);

    // Level schedule (each level's gates depend only on already-materialized rows):
    // [0,32) [32,63) [63,95) [95,111) [111,119) [119,123) [123,125) [125,126) + tail [126,128)
    const int levs[8][2] = {{0,32},{32,31},{63,32},{95,16},{111,8},{119,4},{123,2},{125,1}};
    const dim3 ggrid(LL, NSB);

    for (int layer = 0; layer < 2; ++layer) {
        const u16* xt = layer ? h1 : nullptr;
        u16* hh       = layer ? h2 : h1;
        float* pl     = layer ? pool : nullptr;
        for (int k = 0; k < 8; ++k) {
            const int r0 = levs[k][0], nr = levs[k][1];
            const int nt = (nr * 128 < 1024) ? nr * 128 : 1024;
            if (layer == 0 && k < 2) {
                sepgates_kernel<<<ggrid, 1024, 0, stream>>>(
                    xe_all, inv_all, conv_w, conv_b, gfg, gic, gog, r0, nr);
            } else {
                gates_kernel<<<ggrid, nt, 0, stream>>>(
                    xe_all, inv_all, conv_w, conv_b, xt, hh,
                    gfg, gic, gog, layer, r0, nr);
            }
            scan_kernel<<<dim3(nr, NSB), 128, 0, stream>>>(
                gfg, gic, gog, hh, pl, r0, nr);
        }
        tail2_kernel<<<NSB, 256, 0, stream>>>(hh, layer ? nullptr : h1,
                                              pl, conv_w, conv_b, layer);
    }

    final_kernel<<<BB, 256, 0, stream>>>(pool, lin_w, lin_b, out);
}